// Round 3
// baseline (208.688 us; speedup 1.0000x reference)
//
#include <hip/hip_runtime.h>

#define NSEQ 2048
#define SCALE 0.04419417382415922f
#define LOG2E 1.44269504088896f

typedef __attribute__((ext_vector_type(8))) short short8v;
typedef __attribute__((ext_vector_type(4))) float f32x4;

__device__ __forceinline__ unsigned short f2bf(float f) {
    unsigned int u = __builtin_bit_cast(unsigned int, f);
    u += 0x7fff + ((u >> 16) & 1);
    return (unsigned short)(u >> 16);
}

// ---------------- fp32 -> bf16 convert ----------------
__global__ __launch_bounds__(256) void cvt_bf16(const float* __restrict__ in,
                                                unsigned short* __restrict__ out, int n4) {
    int i = blockIdx.x * 256 + threadIdx.x;
    if (i < n4) {
        float4 v = ((const float4*)in)[i];
        ushort4 o;
        o.x = f2bf(v.x); o.y = f2bf(v.y); o.z = f2bf(v.z); o.w = f2bf(v.w);
        ((ushort4*)out)[i] = o;
    }
}

// ---------------- bf16 GEMM: C[M,N] = A[M,512] * W[N,512]^T + bias ----------------
// MODE 0: N=1536, scatter to Q (scaled by SCALE*LOG2E), K, V^T workspaces (bf16)
// MODE 1: N=512, write fp32 to Cout
template<int MODE>
__global__ __launch_bounds__(256) void gemm_bf16(
    const unsigned short* __restrict__ A,
    const unsigned short* __restrict__ W,
    const float* __restrict__ bias,
    unsigned short* __restrict__ Qws,
    unsigned short* __restrict__ Kws,
    unsigned short* __restrict__ Vtws,
    float* __restrict__ Cout)
{
    const int K = 512;
    const int BKP = 56;
    __shared__ __attribute__((aligned(16))) unsigned short As[128 * BKP];
    __shared__ __attribute__((aligned(16))) unsigned short Bs[128 * BKP];

    int tid = threadIdx.x;
    int lane = tid & 63, w = tid >> 6;
    int wm = w >> 1, wn = w & 1;
    int g = lane >> 4, fr = lane & 15;
    int m0 = blockIdx.y * 128, n0 = blockIdx.x * 128;

    f32x4 acc[4][4] = {};

    for (int k0 = 0; k0 < K; k0 += 32) {
        __syncthreads();
#pragma unroll
        for (int c = 0; c < 2; ++c) {
            int chunk = tid + c * 256;
            int row = chunk >> 2, col = (chunk & 3) * 8;
            short8v av = *(const short8v*)(A + (size_t)(m0 + row) * K + k0 + col);
            *(short8v*)(&As[row * BKP + col]) = av;
            short8v bv = *(const short8v*)(W + (size_t)(n0 + row) * K + k0 + col);
            *(short8v*)(&Bs[row * BKP + col]) = bv;
        }
        __syncthreads();
        short8v af[4], bf[4];
#pragma unroll
        for (int mi = 0; mi < 4; ++mi)
            af[mi] = *(const short8v*)(&As[(wm * 64 + mi * 16 + fr) * BKP + g * 8]);
#pragma unroll
        for (int ni = 0; ni < 4; ++ni)
            bf[ni] = *(const short8v*)(&Bs[(wn * 64 + ni * 16 + fr) * BKP + g * 8]);
#pragma unroll
        for (int mi = 0; mi < 4; ++mi)
#pragma unroll
            for (int ni = 0; ni < 4; ++ni)
                acc[mi][ni] = __builtin_amdgcn_mfma_f32_16x16x32_bf16(
                    af[mi], bf[ni], acc[mi][ni], 0, 0, 0);
    }

#pragma unroll
    for (int mi = 0; mi < 4; ++mi) {
#pragma unroll
        for (int ni = 0; ni < 4; ++ni) {
            int col = n0 + wn * 64 + ni * 16 + fr;
            float bb = bias[col];
#pragma unroll
            for (int r = 0; r < 4; ++r) {
                int row = m0 + wm * 64 + mi * 16 + g * 4 + r;
                float val = acc[mi][ni][r] + bb;
                if (MODE == 0) {
                    int b = row >> 11, s = row & 2047;
                    if (col < 512) {
                        int h = col >> 6, d = col & 63;
                        Qws[(((size_t)(b * 8 + h) * NSEQ + s) << 6) + d] = f2bf(val * (SCALE * LOG2E));
                    } else if (col < 1024) {
                        int c2 = col - 512; int h = c2 >> 6, d = c2 & 63;
                        Kws[(((size_t)(b * 8 + h) * NSEQ + s) << 6) + d] = f2bf(val);
                    } else {
                        int c2 = col - 1024; int h = c2 >> 6, d = c2 & 63;
                        Vtws[((size_t)(b * 8 + h) * 64 + d) * NSEQ + s] = f2bf(val);
                    }
                } else {
                    Cout[(size_t)row * 512 + col] = val;
                }
            }
        }
    }
}

// ---------------- fused attention, fixed-max softmax, barrier-free ----------------
// Block = 512 threads = 8 waves = 8 heads; covers one (b, 32-row q tile).
// Q pre-scaled by SCALE*LOG2E. P = exp2(S + g2*A_phi), l accumulated per-lane.
__global__ __launch_bounds__(512, 2) void attn_kernel(
    const unsigned short* __restrict__ Qws,
    const unsigned short* __restrict__ Kws,
    const unsigned short* __restrict__ Vtws,
    const float* __restrict__ A_phi,
    const float* __restrict__ gamma_p,
    unsigned short* __restrict__ Oout)
{
    __shared__ __attribute__((aligned(16))) unsigned short Pl[8][32 * 72];

    int tid = threadIdx.x, lane = tid & 63, w = tid >> 6;
    int g = lane >> 4, fr = lane & 15;

    // XCD swizzle: group all blocks of one batch b onto one XCD pair
    int id = blockIdx.x + 64 * blockIdx.y;          // 0..255
    int b = (id & 7) >> 1;
    int qt = ((id >> 3) << 1) | (id & 1);
    int q0 = qt * 32;
    int h = w;
    int bh = b * 8 + h;
    float g2 = gamma_p[0] * LOG2E;

    const unsigned short* Qbase = Qws + ((size_t)bh * NSEQ + q0) * 64;
    short8v qf[2][2];
#pragma unroll
    for (int qs = 0; qs < 2; ++qs)
#pragma unroll
        for (int dc = 0; dc < 2; ++dc)
            qf[qs][dc] = *(const short8v*)(Qbase + (size_t)(qs * 16 + fr) * 64 + dc * 32 + g * 8);

    float l_lane[2][4] = {};
    f32x4 o_acc[2][4] = {};

    const float* Ap = A_phi + (size_t)b * NSEQ * NSEQ + (size_t)q0 * NSEQ;
    const unsigned short* Kb = Kws + (size_t)bh * NSEQ * 64;
    const unsigned short* Vb = Vtws + (size_t)bh * 64 * NSEQ;

    for (int kt = 0; kt < NSEQ / 64; ++kt) {
        // K fragments, permuted rows: B-col fr of chunk kf = key 4*fr+kf
        short8v kfrag[4][2];
#pragma unroll
        for (int kf = 0; kf < 4; ++kf)
#pragma unroll
            for (int dc = 0; dc < 2; ++dc)
                kfrag[kf][dc] = *(const short8v*)(Kb + (size_t)(kt * 64 + 4 * fr + kf) * 64 + dc * 32 + g * 8);

        // A_phi tile, coalesced float4 (lane's 4 consecutive keys 4*fr..4*fr+3)
        float4 av[2][4];
#pragma unroll
        for (int qs = 0; qs < 2; ++qs)
#pragma unroll
            for (int r = 0; r < 4; ++r)
                av[qs][r] = *(const float4*)(Ap + (size_t)(qs * 16 + g * 4 + r) * NSEQ + kt * 64 + 4 * fr);

        // S = QK^T (pre-scaled)
        f32x4 sa[2][4] = {};
#pragma unroll
        for (int qs = 0; qs < 2; ++qs)
#pragma unroll
            for (int kf = 0; kf < 4; ++kf)
#pragma unroll
                for (int dc = 0; dc < 2; ++dc)
                    sa[qs][kf] = __builtin_amdgcn_mfma_f32_16x16x32_bf16(
                        qf[qs][dc], kfrag[kf][dc], sa[qs][kf], 0, 0, 0);

        // V fragments (issued early, consumed after relay)
        short8v vfrag[2][4];
#pragma unroll
        for (int kc = 0; kc < 2; ++kc)
#pragma unroll
            for (int nf = 0; nf < 4; ++nf)
                vfrag[kc][nf] = *(const short8v*)(Vb + (size_t)(nf * 16 + fr) * NSEQ + kt * 64 + kc * 32 + g * 8);

        // P = exp2(S + g2*A); accumulate l per-lane; relay P to LDS in natural key order
#pragma unroll
        for (int qs = 0; qs < 2; ++qs) {
#pragma unroll
            for (int r = 0; r < 4; ++r) {
                float e0 = exp2f(fmaf(g2, av[qs][r].x, sa[qs][0][r]));
                float e1 = exp2f(fmaf(g2, av[qs][r].y, sa[qs][1][r]));
                float e2 = exp2f(fmaf(g2, av[qs][r].z, sa[qs][2][r]));
                float e3 = exp2f(fmaf(g2, av[qs][r].w, sa[qs][3][r]));
                l_lane[qs][r] += (e0 + e1) + (e2 + e3);
                int row = qs * 16 + g * 4 + r;
                unsigned int p01 = (unsigned int)f2bf(e0) | ((unsigned int)f2bf(e1) << 16);
                unsigned int p23 = (unsigned int)f2bf(e2) | ((unsigned int)f2bf(e3) << 16);
                *(unsigned int*)(&Pl[w][row * 72 + 4 * fr])     = p01;
                *(unsigned int*)(&Pl[w][row * 72 + 4 * fr + 2]) = p23;
            }
        }
        asm volatile("s_waitcnt lgkmcnt(0)" ::: "memory");

        // O += P * V
#pragma unroll
        for (int qs = 0; qs < 2; ++qs) {
#pragma unroll
            for (int kc = 0; kc < 2; ++kc) {
                short8v pf = *(const short8v*)(&Pl[w][(qs * 16 + fr) * 72 + kc * 32 + g * 8]);
#pragma unroll
                for (int nf = 0; nf < 4; ++nf)
                    o_acc[qs][nf] = __builtin_amdgcn_mfma_f32_16x16x32_bf16(
                        pf, vfrag[kc][nf], o_acc[qs][nf], 0, 0, 0);
            }
        }
    }

    // epilogue: reduce l across the 16-lane group, normalize, store bf16
#pragma unroll
    for (int qs = 0; qs < 2; ++qs) {
#pragma unroll
        for (int r = 0; r < 4; ++r) {
            float l = l_lane[qs][r];
            l += __shfl_xor(l, 1);
            l += __shfl_xor(l, 2);
            l += __shfl_xor(l, 4);
            l += __shfl_xor(l, 8);
            float inv = 1.0f / l;
            int qg = q0 + qs * 16 + g * 4 + r;
#pragma unroll
            for (int nf = 0; nf < 4; ++nf)
                Oout[((size_t)b * NSEQ + qg) * 512 + h * 64 + nf * 16 + fr] =
                    f2bf(o_acc[qs][nf][r] * inv);
        }
    }
}

extern "C" void kernel_launch(void* const* d_in, const int* in_sizes, int n_in,
                              void* d_out, int out_size, void* d_ws, size_t ws_size,
                              hipStream_t stream) {
    const float* x      = (const float*)d_in[0];
    const float* A_phi  = (const float*)d_in[1];
    const float* w_qkv  = (const float*)d_in[2];
    const float* b_qkv  = (const float*)d_in[3];
    const float* w_out  = (const float*)d_in[4];
    const float* b_out  = (const float*)d_in[5];
    const float* gamma  = (const float*)d_in[6];
    float* out = (float*)d_out;

    unsigned short* xb   = (unsigned short*)d_ws;
    unsigned short* wqb  = xb  + (size_t)8192 * 512;
    unsigned short* wob  = wqb + (size_t)1536 * 512;
    unsigned short* Qws  = wob + (size_t)512 * 512;
    unsigned short* Kws  = Qws + (size_t)4 * 8 * NSEQ * 64;
    unsigned short* Vtws = Kws + (size_t)4 * 8 * NSEQ * 64;
    unsigned short* Oat  = Vtws + (size_t)4 * 8 * NSEQ * 64;

    cvt_bf16<<<dim3(4096), dim3(256), 0, stream>>>(x, xb, 8192 * 512 / 4);
    cvt_bf16<<<dim3(768),  dim3(256), 0, stream>>>(w_qkv, wqb, 1536 * 512 / 4);
    cvt_bf16<<<dim3(256),  dim3(256), 0, stream>>>(w_out, wob, 512 * 512 / 4);

    gemm_bf16<0><<<dim3(12, 64), dim3(256), 0, stream>>>(
        xb, wqb, b_qkv, Qws, Kws, Vtws, nullptr);

    attn_kernel<<<dim3(64, 4), dim3(512), 0, stream>>>(
        Qws, Kws, Vtws, A_phi, gamma, Oat);

    gemm_bf16<1><<<dim3(4, 64), dim3(256), 0, stream>>>(
        Oat, wob, b_out, nullptr, nullptr, nullptr, out);
}

// Round 4
// 135.989 us; speedup vs baseline: 1.5346x; 1.5346x over previous
//
#include <hip/hip_runtime.h>

#define NSEQ 2048
#define SCALE 0.04419417382415922f
#define LOG2E 1.44269504088896f

typedef __attribute__((ext_vector_type(8))) short short8v;
typedef __attribute__((ext_vector_type(4))) float f32x4;

__device__ __forceinline__ unsigned short f2bf(float f) {
    unsigned int u = __builtin_bit_cast(unsigned int, f);
    u += 0x7fff + ((u >> 16) & 1);
    return (unsigned short)(u >> 16);
}

__device__ __forceinline__ float exp2_fast(float x) {
    float r; asm("v_exp_f32 %0, %1" : "=v"(r) : "v"(x)); return r;
}

// ---------------- fp32 -> bf16 convert ----------------
__global__ __launch_bounds__(256) void cvt_bf16(const float* __restrict__ in,
                                                unsigned short* __restrict__ out, int n4) {
    int i = blockIdx.x * 256 + threadIdx.x;
    if (i < n4) {
        float4 v = ((const float4*)in)[i];
        ushort4 o;
        o.x = f2bf(v.x); o.y = f2bf(v.y); o.z = f2bf(v.z); o.w = f2bf(v.w);
        ((ushort4*)out)[i] = o;
    }
}

// ---------------- bf16 GEMM: C[M,N] = A[M,512] * W[N,512]^T + bias ----------------
template<int MODE>
__global__ __launch_bounds__(256) void gemm_bf16(
    const unsigned short* __restrict__ A,
    const unsigned short* __restrict__ W,
    const float* __restrict__ bias,
    unsigned short* __restrict__ Qws,
    unsigned short* __restrict__ Kws,
    unsigned short* __restrict__ Vtws,
    float* __restrict__ Cout)
{
    const int K = 512;
    const int BKP = 56;
    __shared__ __attribute__((aligned(16))) unsigned short As[128 * BKP];
    __shared__ __attribute__((aligned(16))) unsigned short Bs[128 * BKP];

    int tid = threadIdx.x;
    int lane = tid & 63, w = tid >> 6;
    int wm = w >> 1, wn = w & 1;
    int g = lane >> 4, fr = lane & 15;
    int m0 = blockIdx.y * 128, n0 = blockIdx.x * 128;

    f32x4 acc[4][4] = {};

    for (int k0 = 0; k0 < K; k0 += 32) {
        __syncthreads();
#pragma unroll
        for (int c = 0; c < 2; ++c) {
            int chunk = tid + c * 256;
            int row = chunk >> 2, col = (chunk & 3) * 8;
            short8v av = *(const short8v*)(A + (size_t)(m0 + row) * K + k0 + col);
            *(short8v*)(&As[row * BKP + col]) = av;
            short8v bv = *(const short8v*)(W + (size_t)(n0 + row) * K + k0 + col);
            *(short8v*)(&Bs[row * BKP + col]) = bv;
        }
        __syncthreads();
        short8v af[4], bf[4];
#pragma unroll
        for (int mi = 0; mi < 4; ++mi)
            af[mi] = *(const short8v*)(&As[(wm * 64 + mi * 16 + fr) * BKP + g * 8]);
#pragma unroll
        for (int ni = 0; ni < 4; ++ni)
            bf[ni] = *(const short8v*)(&Bs[(wn * 64 + ni * 16 + fr) * BKP + g * 8]);
#pragma unroll
        for (int mi = 0; mi < 4; ++mi)
#pragma unroll
            for (int ni = 0; ni < 4; ++ni)
                acc[mi][ni] = __builtin_amdgcn_mfma_f32_16x16x32_bf16(
                    af[mi], bf[ni], acc[mi][ni], 0, 0, 0);
    }

#pragma unroll
    for (int mi = 0; mi < 4; ++mi) {
#pragma unroll
        for (int ni = 0; ni < 4; ++ni) {
            int col = n0 + wn * 64 + ni * 16 + fr;
            float bb = bias[col];
#pragma unroll
            for (int r = 0; r < 4; ++r) {
                int row = m0 + wm * 64 + mi * 16 + g * 4 + r;
                float val = acc[mi][ni][r] + bb;
                if (MODE == 0) {
                    int b = row >> 11, s = row & 2047;
                    if (col < 512) {
                        int h = col >> 6, d = col & 63;
                        Qws[(((size_t)(b * 8 + h) * NSEQ + s) << 6) + d] = f2bf(val * (SCALE * LOG2E));
                    } else if (col < 1024) {
                        int c2 = col - 512; int h = c2 >> 6, d = c2 & 63;
                        Kws[(((size_t)(b * 8 + h) * NSEQ + s) << 6) + d] = f2bf(val);
                    } else {
                        int c2 = col - 1024; int h = c2 >> 6, d = c2 & 63;
                        Vtws[((size_t)(b * 8 + h) * 64 + d) * NSEQ + s] = f2bf(val);
                    }
                } else {
                    Cout[(size_t)row * 512 + col] = val;
                }
            }
        }
    }
}

// ---------------- fused attention ----------------
// Block = 512 thr = 8 waves, one (b,h); wave w owns 16 q-rows.
// K/V tiles (64 keys) staged in double-buffered padded LDS, shared by all waves.
// Fixed-max softmax: P = exp2(S + g2*A_phi). Q pre-scaled by SCALE*LOG2E.
__global__ __launch_bounds__(512, 4) void attn_kernel(
    const unsigned short* __restrict__ Qws,
    const unsigned short* __restrict__ Kws,
    const unsigned short* __restrict__ Vtws,
    const float* __restrict__ A_phi,
    const float* __restrict__ gamma_p,
    unsigned short* __restrict__ Oout)
{
    __shared__ __attribute__((aligned(16))) unsigned short Ks[2][64 * 72];
    __shared__ __attribute__((aligned(16))) unsigned short Vts[2][64 * 72];
    __shared__ __attribute__((aligned(16))) unsigned short Pl[8][16 * 72];

    int tid = threadIdx.x, lane = tid & 63, w = tid >> 6;
    int g = lane >> 4, fr = lane & 15;

    // swizzle: id%8 = XCD → pin batch b to an XCD pair (A_phi L2 reuse)
    int id = blockIdx.x;                 // 0..511
    int b = (id & 7) >> 1, p = id & 1;
    int j = id >> 3;                     // 0..63
    int h = j & 7;
    int qt = ((j >> 3) << 1) | p;        // 0..15
    int bh = b * 8 + h;
    int q0 = qt * 128 + w * 16;          // wave's q base
    float g2 = gamma_p[0] * LOG2E;

    const unsigned short* Kb = Kws + (size_t)bh * NSEQ * 64;
    const unsigned short* Vb = Vtws + (size_t)bh * 64 * NSEQ;
    const float* Ap = A_phi + (size_t)b * NSEQ * NSEQ;

    // Q fragments
    short8v qf[2];
#pragma unroll
    for (int dc = 0; dc < 2; ++dc)
        qf[dc] = *(const short8v*)(Qws + ((size_t)bh * NSEQ + q0 + fr) * 64 + dc * 32 + g * 8);

    // staging assignment: thread -> one 16B K chunk + one 16B V chunk
    int c = tid;                         // 0..511
    int krow = c >> 3, kcol = (c & 7) * 8;   // K: row=key(0..63); V: row=d(0..63)

    float l_lane[4] = {};
    f32x4 o_acc[4] = {};

    // prologue: stage tile 0
    {
        short8v k0v = *(const short8v*)(Kb + c * 8);
        short8v v0v = *(const short8v*)(Vb + (size_t)krow * NSEQ + kcol);
        *(short8v*)(&Ks[0][krow * 72 + kcol]) = k0v;
        *(short8v*)(&Vts[0][krow * 72 + kcol]) = v0v;
    }
    __syncthreads();

    for (int kt = 0; kt < NSEQ / 64; ++kt) {
        int cur = kt & 1;

        // T14: issue next-tile global loads early
        short8v kreg, vreg;
        if (kt < NSEQ / 64 - 1) {
            kreg = *(const short8v*)(Kb + (kt + 1) * 4096 + c * 8);
            vreg = *(const short8v*)(Vb + (size_t)krow * NSEQ + (kt + 1) * 64 + kcol);
        }

        // A_phi tile (coalesced float4; lane's 4 consecutive keys 4*fr..4*fr+3)
        float4 av[4];
#pragma unroll
        for (int r = 0; r < 4; ++r)
            av[r] = *(const float4*)(Ap + (size_t)(q0 + g * 4 + r) * NSEQ + kt * 64 + 4 * fr);

        // S = QK^T, permuted key order: chunk kf col fr = key 4*fr+kf
        f32x4 sa[4] = {};
#pragma unroll
        for (int kf = 0; kf < 4; ++kf)
#pragma unroll
            for (int dc = 0; dc < 2; ++dc) {
                short8v kfrag = *(const short8v*)(&Ks[cur][(4 * fr + kf) * 72 + dc * 32 + g * 8]);
                sa[kf] = __builtin_amdgcn_mfma_f32_16x16x32_bf16(qf[dc], kfrag, sa[kf], 0, 0, 0);
            }

        // P = exp2(S + g2*A); per-lane l; relay to per-wave LDS in natural key order
#pragma unroll
        for (int r = 0; r < 4; ++r) {
            float e0 = exp2_fast(fmaf(g2, av[r].x, sa[0][r]));
            float e1 = exp2_fast(fmaf(g2, av[r].y, sa[1][r]));
            float e2 = exp2_fast(fmaf(g2, av[r].z, sa[2][r]));
            float e3 = exp2_fast(fmaf(g2, av[r].w, sa[3][r]));
            l_lane[r] += (e0 + e1) + (e2 + e3);
            int row = g * 4 + r;
            uint2 pp;
            pp.x = (unsigned int)f2bf(e0) | ((unsigned int)f2bf(e1) << 16);
            pp.y = (unsigned int)f2bf(e2) | ((unsigned int)f2bf(e3) << 16);
            *(uint2*)(&Pl[w][row * 72 + 4 * fr]) = pp;
        }
        asm volatile("s_waitcnt lgkmcnt(0)" ::: "memory");

        // O += P * V
#pragma unroll
        for (int kc = 0; kc < 2; ++kc) {
            short8v pf = *(const short8v*)(&Pl[w][fr * 72 + kc * 32 + g * 8]);
#pragma unroll
            for (int nf = 0; nf < 4; ++nf) {
                short8v vfrag = *(const short8v*)(&Vts[cur][(nf * 16 + fr) * 72 + kc * 32 + g * 8]);
                o_acc[nf] = __builtin_amdgcn_mfma_f32_16x16x32_bf16(pf, vfrag, o_acc[nf], 0, 0, 0);
            }
        }

        // write staged regs into the other buffer, then block-wide barrier
        if (kt < NSEQ / 64 - 1) {
            *(short8v*)(&Ks[cur ^ 1][krow * 72 + kcol]) = kreg;
            *(short8v*)(&Vts[cur ^ 1][krow * 72 + kcol]) = vreg;
        }
        __syncthreads();
    }

    // epilogue: reduce l across 16-lane group, normalize, store bf16
#pragma unroll
    for (int r = 0; r < 4; ++r) {
        float l = l_lane[r];
        l += __shfl_xor(l, 1);
        l += __shfl_xor(l, 2);
        l += __shfl_xor(l, 4);
        l += __shfl_xor(l, 8);
        float inv = 1.0f / l;
        int qg = q0 + g * 4 + r;
#pragma unroll
        for (int nf = 0; nf < 4; ++nf)
            Oout[((size_t)b * NSEQ + qg) * 512 + h * 64 + nf * 16 + fr] =
                f2bf(o_acc[nf][r] * inv);
    }
}

extern "C" void kernel_launch(void* const* d_in, const int* in_sizes, int n_in,
                              void* d_out, int out_size, void* d_ws, size_t ws_size,
                              hipStream_t stream) {
    const float* x      = (const float*)d_in[0];
    const float* A_phi  = (const float*)d_in[1];
    const float* w_qkv  = (const float*)d_in[2];
    const float* b_qkv  = (const float*)d_in[3];
    const float* w_out  = (const float*)d_in[4];
    const float* b_out  = (const float*)d_in[5];
    const float* gamma  = (const float*)d_in[6];
    float* out = (float*)d_out;

    unsigned short* xb   = (unsigned short*)d_ws;
    unsigned short* wqb  = xb  + (size_t)8192 * 512;
    unsigned short* wob  = wqb + (size_t)1536 * 512;
    unsigned short* Qws  = wob + (size_t)512 * 512;
    unsigned short* Kws  = Qws + (size_t)4 * 8 * NSEQ * 64;
    unsigned short* Vtws = Kws + (size_t)4 * 8 * NSEQ * 64;
    unsigned short* Oat  = Vtws + (size_t)4 * 8 * NSEQ * 64;

    cvt_bf16<<<dim3(4096), dim3(256), 0, stream>>>(x, xb, 8192 * 512 / 4);
    cvt_bf16<<<dim3(768),  dim3(256), 0, stream>>>(w_qkv, wqb, 1536 * 512 / 4);
    cvt_bf16<<<dim3(256),  dim3(256), 0, stream>>>(w_out, wob, 512 * 512 / 4);

    gemm_bf16<0><<<dim3(12, 64), dim3(256), 0, stream>>>(
        xb, wqb, b_qkv, Qws, Kws, Vtws, nullptr);

    attn_kernel<<<dim3(512), dim3(512), 0, stream>>>(
        Qws, Kws, Vtws, A_phi, gamma, Oat);

    gemm_bf16<1><<<dim3(4, 64), dim3(256), 0, stream>>>(
        Oat, wob, b_out, nullptr, nullptr, nullptr, out);
}

// Round 5
// 130.353 us; speedup vs baseline: 1.6009x; 1.0432x over previous
//
#include <hip/hip_runtime.h>

#define NSEQ 2048
#define SCALE 0.04419417382415922f
#define LOG2E 1.44269504088896f

typedef __attribute__((ext_vector_type(8))) short short8v;
typedef __attribute__((ext_vector_type(4))) float f32x4;

__device__ __forceinline__ unsigned short f2bf(float f) {
    unsigned int u = __builtin_bit_cast(unsigned int, f);
    u += 0x7fff + ((u >> 16) & 1);
    return (unsigned short)(u >> 16);
}

__device__ __forceinline__ float exp2_fast(float x) {
    float r; asm("v_exp_f32 %0, %1" : "=v"(r) : "v"(x)); return r;
}

// pack(bf16_round(a) lo, bf16_round(b) hi) : 2 adds + 1 v_perm_b32
__device__ __forceinline__ unsigned int pack_bf16_rh(float a, float b) {
    unsigned int ua = __builtin_bit_cast(unsigned int, a) + 0x8000u;
    unsigned int ub = __builtin_bit_cast(unsigned int, b) + 0x8000u;
    return __builtin_amdgcn_perm(ub, ua, 0x07060302u);
}

// ---------------- fp32 -> bf16 convert ----------------
__global__ __launch_bounds__(256) void cvt_bf16(const float* __restrict__ in,
                                                unsigned short* __restrict__ out, int n4) {
    int i = blockIdx.x * 256 + threadIdx.x;
    if (i < n4) {
        float4 v = ((const float4*)in)[i];
        ushort4 o;
        o.x = f2bf(v.x); o.y = f2bf(v.y); o.z = f2bf(v.z); o.w = f2bf(v.w);
        ((ushort4*)out)[i] = o;
    }
}

// ---------------- bf16 GEMM, BK=64: C[M,N] = A[M,512] * W[N,512]^T + bias ----------------
template<int MODE>
__global__ __launch_bounds__(256) void gemm_bf16(
    const unsigned short* __restrict__ A,
    const unsigned short* __restrict__ W,
    const float* __restrict__ bias,
    unsigned short* __restrict__ Qws,
    unsigned short* __restrict__ Kws,
    unsigned short* __restrict__ Vtws,
    float* __restrict__ Cout)
{
    const int K = 512;
    const int BKP = 72;   // 64 + 8 pad (144B row, 2-way banks max on frag reads)
    __shared__ __attribute__((aligned(16))) unsigned short As[128 * BKP];
    __shared__ __attribute__((aligned(16))) unsigned short Bs[128 * BKP];

    int tid = threadIdx.x;
    int lane = tid & 63, w = tid >> 6;
    int wm = w >> 1, wn = w & 1;
    int g = lane >> 4, fr = lane & 15;
    int m0 = blockIdx.y * 128, n0 = blockIdx.x * 128;

    f32x4 acc[4][4] = {};

    for (int k0 = 0; k0 < K; k0 += 64) {
        __syncthreads();
#pragma unroll
        for (int c = 0; c < 4; ++c) {
            int chunk = tid + c * 256;            // 1024 chunks of 8 = 128x64
            int row = chunk >> 3, col = (chunk & 7) * 8;
            short8v av = *(const short8v*)(A + (size_t)(m0 + row) * K + k0 + col);
            *(short8v*)(&As[row * BKP + col]) = av;
            short8v bv = *(const short8v*)(W + (size_t)(n0 + row) * K + k0 + col);
            *(short8v*)(&Bs[row * BKP + col]) = bv;
        }
        __syncthreads();
#pragma unroll
        for (int kk = 0; kk < 2; ++kk) {
            short8v af[4], bf[4];
#pragma unroll
            for (int mi = 0; mi < 4; ++mi)
                af[mi] = *(const short8v*)(&As[(wm * 64 + mi * 16 + fr) * BKP + kk * 32 + g * 8]);
#pragma unroll
            for (int ni = 0; ni < 4; ++ni)
                bf[ni] = *(const short8v*)(&Bs[(wn * 64 + ni * 16 + fr) * BKP + kk * 32 + g * 8]);
#pragma unroll
            for (int mi = 0; mi < 4; ++mi)
#pragma unroll
                for (int ni = 0; ni < 4; ++ni)
                    acc[mi][ni] = __builtin_amdgcn_mfma_f32_16x16x32_bf16(
                        af[mi], bf[ni], acc[mi][ni], 0, 0, 0);
        }
    }

#pragma unroll
    for (int mi = 0; mi < 4; ++mi) {
#pragma unroll
        for (int ni = 0; ni < 4; ++ni) {
            int col = n0 + wn * 64 + ni * 16 + fr;
            float bb = bias[col];
#pragma unroll
            for (int r = 0; r < 4; ++r) {
                int row = m0 + wm * 64 + mi * 16 + g * 4 + r;
                float val = acc[mi][ni][r] + bb;
                if (MODE == 0) {
                    int b = row >> 11, s = row & 2047;
                    if (col < 512) {
                        int h = col >> 6, d = col & 63;
                        Qws[(((size_t)(b * 8 + h) * NSEQ + s) << 6) + d] = f2bf(val * (SCALE * LOG2E));
                    } else if (col < 1024) {
                        int c2 = col - 512; int h = c2 >> 6, d = c2 & 63;
                        Kws[(((size_t)(b * 8 + h) * NSEQ + s) << 6) + d] = f2bf(val);
                    } else {
                        int c2 = col - 1024; int h = c2 >> 6, d = c2 & 63;
                        Vtws[((size_t)(b * 8 + h) * 64 + d) * NSEQ + s] = f2bf(val);
                    }
                } else {
                    Cout[(size_t)row * 512 + col] = val;
                }
            }
        }
    }
}

// ---------------- fused attention ----------------
// Block = 512 thr = 8 waves, one (b,h); wave w owns 32 q-rows (two 16-row halves).
// K/V tiles (64 keys) double-buffered in padded LDS, shared by all waves.
// Fixed-max softmax: P = exp2(S + g2*A_phi). Q pre-scaled by SCALE*LOG2E.
__global__ __launch_bounds__(512, 4) void attn_kernel(
    const unsigned short* __restrict__ Qws,
    const unsigned short* __restrict__ Kws,
    const unsigned short* __restrict__ Vtws,
    const float* __restrict__ A_phi,
    const float* __restrict__ gamma_p,
    unsigned short* __restrict__ Oout)
{
    __shared__ __attribute__((aligned(16))) unsigned short Ks[2][64 * 72];
    __shared__ __attribute__((aligned(16))) unsigned short Vts[2][64 * 72];
    __shared__ __attribute__((aligned(16))) unsigned short Pl[8][32 * 72];

    int tid = threadIdx.x, lane = tid & 63, w = tid >> 6;
    int g = lane >> 4, fr = lane & 15;

    // swizzle: id%8 = XCD → pin batch b to an XCD pair (A_phi L2 reuse)
    int id = blockIdx.x;                 // 0..255
    int b = (id & 7) >> 1, p = id & 1;
    int j = id >> 3;                     // 0..31
    int h = j & 7;
    int qt = ((j >> 3) << 1) | p;        // 0..7
    int bh = b * 8 + h;
    int q0 = qt * 256 + w * 32;          // wave's q base (32 rows)
    float g2 = gamma_p[0] * LOG2E;

    const unsigned short* Kb = Kws + (size_t)bh * NSEQ * 64;
    const unsigned short* Vb = Vtws + (size_t)bh * 64 * NSEQ;
    const float* Ap = A_phi + (size_t)b * NSEQ * NSEQ;

    // Q fragments for both 16-row halves
    short8v qf[2][2];
#pragma unroll
    for (int qs = 0; qs < 2; ++qs)
#pragma unroll
        for (int dc = 0; dc < 2; ++dc)
            qf[qs][dc] = *(const short8v*)(Qws + ((size_t)bh * NSEQ + q0 + qs * 16 + fr) * 64 + dc * 32 + g * 8);

    // staging: thread -> one 16B K chunk + one 16B V chunk
    int c = tid;
    int krow = c >> 3, kcol = (c & 7) * 8;

    float l_lane[2][4] = {};
    f32x4 o_acc[2][4] = {};

    // prologue: stage tile 0
    {
        short8v k0v = *(const short8v*)(Kb + c * 8);
        short8v v0v = *(const short8v*)(Vb + (size_t)krow * NSEQ + kcol);
        *(short8v*)(&Ks[0][krow * 72 + kcol]) = k0v;
        *(short8v*)(&Vts[0][krow * 72 + kcol]) = v0v;
    }
    __syncthreads();

    for (int kt = 0; kt < NSEQ / 64; ++kt) {
        int cur = kt & 1;

        // prefetch next tile into registers early (T14)
        short8v kreg, vreg;
        if (kt < NSEQ / 64 - 1) {
            kreg = *(const short8v*)(Kb + (kt + 1) * 4096 + c * 8);
            vreg = *(const short8v*)(Vb + (size_t)krow * NSEQ + (kt + 1) * 64 + kcol);
        }

        // QK^T + softmax per 16-row half
#pragma unroll
        for (int qs = 0; qs < 2; ++qs) {
            float4 av[4];
#pragma unroll
            for (int r = 0; r < 4; ++r)
                av[r] = *(const float4*)(Ap + (size_t)(q0 + qs * 16 + g * 4 + r) * NSEQ + kt * 64 + 4 * fr);

            f32x4 sa[4] = {};
            __builtin_amdgcn_s_setprio(1);
#pragma unroll
            for (int kf = 0; kf < 4; ++kf)
#pragma unroll
                for (int dc = 0; dc < 2; ++dc) {
                    short8v kfrag = *(const short8v*)(&Ks[cur][(4 * fr + kf) * 72 + dc * 32 + g * 8]);
                    sa[kf] = __builtin_amdgcn_mfma_f32_16x16x32_bf16(qf[qs][dc], kfrag, sa[kf], 0, 0, 0);
                }
            __builtin_amdgcn_s_setprio(0);

#pragma unroll
            for (int r = 0; r < 4; ++r) {
                float e0 = exp2_fast(fmaf(g2, av[r].x, sa[0][r]));
                float e1 = exp2_fast(fmaf(g2, av[r].y, sa[1][r]));
                float e2 = exp2_fast(fmaf(g2, av[r].z, sa[2][r]));
                float e3 = exp2_fast(fmaf(g2, av[r].w, sa[3][r]));
                l_lane[qs][r] += (e0 + e1) + (e2 + e3);
                uint2 pp;
                pp.x = pack_bf16_rh(e0, e1);
                pp.y = pack_bf16_rh(e2, e3);
                *(uint2*)(&Pl[w][(qs * 16 + g * 4 + r) * 72 + 4 * fr]) = pp;
            }
        }
        asm volatile("s_waitcnt lgkmcnt(0)" ::: "memory");

        // PV for both halves, V-frags read once
#pragma unroll
        for (int kc = 0; kc < 2; ++kc) {
            short8v pf0 = *(const short8v*)(&Pl[w][(fr) * 72 + kc * 32 + g * 8]);
            short8v pf1 = *(const short8v*)(&Pl[w][(16 + fr) * 72 + kc * 32 + g * 8]);
            __builtin_amdgcn_s_setprio(1);
#pragma unroll
            for (int nf = 0; nf < 4; ++nf) {
                short8v vf = *(const short8v*)(&Vts[cur][(nf * 16 + fr) * 72 + kc * 32 + g * 8]);
                o_acc[0][nf] = __builtin_amdgcn_mfma_f32_16x16x32_bf16(pf0, vf, o_acc[0][nf], 0, 0, 0);
                o_acc[1][nf] = __builtin_amdgcn_mfma_f32_16x16x32_bf16(pf1, vf, o_acc[1][nf], 0, 0, 0);
            }
            __builtin_amdgcn_s_setprio(0);
        }

        // write staged regs into the other buffer, then block-wide barrier
        if (kt < NSEQ / 64 - 1) {
            *(short8v*)(&Ks[cur ^ 1][krow * 72 + kcol]) = kreg;
            *(short8v*)(&Vts[cur ^ 1][krow * 72 + kcol]) = vreg;
        }
        __syncthreads();
    }

    // epilogue: reduce l across 16-lane group, normalize, store bf16
#pragma unroll
    for (int qs = 0; qs < 2; ++qs) {
#pragma unroll
        for (int r = 0; r < 4; ++r) {
            float l = l_lane[qs][r];
            l += __shfl_xor(l, 1);
            l += __shfl_xor(l, 2);
            l += __shfl_xor(l, 4);
            l += __shfl_xor(l, 8);
            float inv = 1.0f / l;
            int qg = q0 + qs * 16 + g * 4 + r;
#pragma unroll
            for (int nf = 0; nf < 4; ++nf)
                Oout[((size_t)b * NSEQ + qg) * 512 + h * 64 + nf * 16 + fr] =
                    f2bf(o_acc[qs][nf][r] * inv);
        }
    }
}

extern "C" void kernel_launch(void* const* d_in, const int* in_sizes, int n_in,
                              void* d_out, int out_size, void* d_ws, size_t ws_size,
                              hipStream_t stream) {
    const float* x      = (const float*)d_in[0];
    const float* A_phi  = (const float*)d_in[1];
    const float* w_qkv  = (const float*)d_in[2];
    const float* b_qkv  = (const float*)d_in[3];
    const float* w_out  = (const float*)d_in[4];
    const float* b_out  = (const float*)d_in[5];
    const float* gamma  = (const float*)d_in[6];
    float* out = (float*)d_out;

    unsigned short* xb   = (unsigned short*)d_ws;
    unsigned short* wqb  = xb  + (size_t)8192 * 512;
    unsigned short* wob  = wqb + (size_t)1536 * 512;
    unsigned short* Qws  = wob + (size_t)512 * 512;
    unsigned short* Kws  = Qws + (size_t)4 * 8 * NSEQ * 64;
    unsigned short* Vtws = Kws + (size_t)4 * 8 * NSEQ * 64;
    unsigned short* Oat  = Vtws + (size_t)4 * 8 * NSEQ * 64;

    cvt_bf16<<<dim3(4096), dim3(256), 0, stream>>>(x, xb, 8192 * 512 / 4);
    cvt_bf16<<<dim3(768),  dim3(256), 0, stream>>>(w_qkv, wqb, 1536 * 512 / 4);
    cvt_bf16<<<dim3(256),  dim3(256), 0, stream>>>(w_out, wob, 512 * 512 / 4);

    gemm_bf16<0><<<dim3(12, 64), dim3(256), 0, stream>>>(
        xb, wqb, b_qkv, Qws, Kws, Vtws, nullptr);

    attn_kernel<<<dim3(256), dim3(512), 0, stream>>>(
        Qws, Kws, Vtws, A_phi, gamma, Oat);

    gemm_bf16<1><<<dim3(4, 64), dim3(256), 0, stream>>>(
        Oat, wob, b_out, nullptr, nullptr, nullptr, out);
}